// Round 9
// baseline (24860.791 us; speedup 1.0000x reference)
//
#include <hip/hip_runtime.h>

// Residual VQ, bit-exact vs numpy. B=16 S=2048 D=64 K=8 M=2048.
//
// Numerics contract (verified bit-exact R1-R7, absmax 0.0):
//  - r2/c2: numpy pairwise_sum 8-accumulator order, no FMA contraction
//  - cross: numpy einsum SSE order: 4 chains (d mod 4), per 16-block groups
//           {12,8,4,0}+j, blocks ascending, zero-init chains, hsum (L0+L1)+(L2+L3)
//  - t = fl(r2 - 2*cross) via fmaf(-2,cross,r2); d2 = fl(t + c2)
//  - argmin: first occurrence (strict <, ascending m)
//
// R9 = R8 architecture with the crash fixed. R8's ws layout ran to 14.4 MB
// (never checked vs ws_size; known-good is only >=8.07 MB from R7) -> OOB
// fault -> stream aborted -> d_out stayed zeroed (exact R0 stub signature:
// output0 pass, output1 absmax 2048). Fixes:
//  - residual update is per-element, hence in-place safe: residual lives in
//    the quant region of d_out for all steps (k=0 reads x). No 8 MB ping-pong.
//  - one shared worklist (steps serialized in-stream), WLCAP 393216 (1.5 MB).
//  - ws total 3.9 MB << 8.07 MB known-good.
//  - margin re-derived with correct bf16 half-ulp 2^-8: |proxy err| <= 3.5e-4
//    worst-case, filter needs 2e ~= 7e-4 -> margin 1.5e-3 (2.1x slack);
//    expected candidates ~4.3/pt ~ 140K/step vs cap 393216.
// Pass 1 (rvq_scan): proxy[p][m] = c2[m]/2 - r.c via bf16 MFMA 16x16x32
// (argmin-equivalent to d2; r2 row-constant). Min-sweep + collect-sweep.
// Pass 2 (rvq_exact): exact numpy-order d2 on worklist; winner via u64
// atomicMin((d2bits<<11)|m) -- d2~64>0 so float order == bit order; ties ->
// smaller m = first occurrence.
// MFMA layouts (guide-verified): C/D col=lane&15,row=(lane>>4)*4+reg;
// A[m=lane&15][k=(lane>>4)*8+j]; B[k=(lane>>4)*8+j][n=lane&15].

#define BB 16
#define SS 2048
#define DD 64
#define KK 8
#define MM 2048
#define NPTS (BB * SS)      // 32768
#define QSIZE (NPTS * DD)   // 2097152
#define WLCAP 393216        // shared worklist entries (1.5 MB)
#define MARGIN 1.5e-3f

typedef short v8s __attribute__((ext_vector_type(8)));   // 8 bf16
typedef float v4f __attribute__((ext_vector_type(4)));

static __device__ __forceinline__ unsigned short f2bf(float f) {  // RNE
    union { float f; unsigned u; } x; x.f = f;
    return (unsigned short)((x.u + 0x7fffu + ((x.u >> 16) & 1u)) >> 16);
}

// ---- prep: exact c2 (numpy pairwise), c2h = c2/2, bf16 codebook, zero cnts ----
__global__ __launch_bounds__(256) void rvq_prep(const float* __restrict__ cb,
                                                float* __restrict__ c2,
                                                float* __restrict__ c2h,
                                                unsigned short* __restrict__ cbh,
                                                unsigned* __restrict__ cnt) {
#pragma clang fp contract(off)
    int tid = blockIdx.x * 256 + threadIdx.x;  // 0 .. K*M-1
    if (tid < KK) cnt[tid] = 0;
    const float* row = cb + (size_t)tid * DD;
    float r[8];
#pragma unroll
    for (int j = 0; j < 8; ++j) { float v = row[j]; r[j] = v * v; }
#pragma unroll
    for (int i = 8; i < DD; i += 8) {
#pragma unroll
        for (int j = 0; j < 8; ++j) { float v = row[i + j]; float t = v * v; r[j] += t; }
    }
    float s = ((r[0] + r[1]) + (r[2] + r[3])) + ((r[4] + r[5]) + (r[6] + r[7]));
    c2[tid] = s;
    c2h[tid] = 0.5f * s;   // exact (x0.5)
#pragma unroll
    for (int d = 0; d < DD; ++d) cbh[(size_t)tid * DD + d] = f2bf(row[d]);
}

// ---- scan: MFMA proxy sweep -> per-point min -> candidate collection ----
// grid 512 blocks x 512 threads (8 waves). Wave w: point-group g=w>>1 (16
// points), m-half = w&1 (1024 m). Tile = 16x16, K=64 via 2 MFMA.
__global__ __launch_bounds__(512) void rvq_scan(const float* __restrict__ res_in,
                                                const unsigned short* __restrict__ cbh, // (M,D) bf16, this k
                                                const float* __restrict__ c2h,          // (M,) this k
                                                unsigned long long* __restrict__ pmn,   // (NPTS,)
                                                unsigned* __restrict__ wl,              // shared
                                                unsigned* __restrict__ cnt) {           // this k
    __shared__ float c2s[MM];
    __shared__ float smin[4][16][2];
    const int tid = threadIdx.x;
    for (int i = tid; i < MM; i += 512) c2s[i] = c2h[i];

    const int lane = tid & 63;
    const int wv = tid >> 6;
    const int g = wv >> 1, half = wv & 1;
    const int quad = lane >> 4, col = lane & 15;
    const int p0 = blockIdx.x * 64 + g * 16;

    // A-fragments (fixed per wave): A[m=col][k=quad*8+j] = -res[p0+col][k]
    const float* rrow = res_in + (size_t)(p0 + col) * DD + quad * 8;
    v8s a_lo, a_hi;
#pragma unroll
    for (int j = 0; j < 8; ++j) {
        a_lo[j] = (short)f2bf(-rrow[j]);
        a_hi[j] = (short)f2bf(-rrow[32 + j]);
    }
    __syncthreads();  // c2s ready

    const int mbase = half * (MM / 2);
    float rm[4] = {__builtin_inff(), __builtin_inff(), __builtin_inff(), __builtin_inff()};
#pragma unroll 2
    for (int t = 0; t < 64; ++t) {
        const int m = mbase + t * 16 + col;
        const v8s b_lo = *(const v8s*)(cbh + (size_t)m * DD + quad * 8);
        const v8s b_hi = *(const v8s*)(cbh + (size_t)m * DD + 32 + quad * 8);
        v4f acc = {0.f, 0.f, 0.f, 0.f};
        acc = __builtin_amdgcn_mfma_f32_16x16x32_bf16(a_lo, b_lo, acc, 0, 0, 0);
        acc = __builtin_amdgcn_mfma_f32_16x16x32_bf16(a_hi, b_hi, acc, 0, 0, 0);
        const float c2v = c2s[m];
#pragma unroll
        for (int r = 0; r < 4; ++r) rm[r] = fminf(rm[r], acc[r] + c2v);
    }
    // reduce over the 16 column-holder lanes (xor 1,2,4,8 stays within quad)
#pragma unroll
    for (int off = 1; off <= 8; off <<= 1) {
#pragma unroll
        for (int r = 0; r < 4; ++r) rm[r] = fminf(rm[r], __shfl_xor(rm[r], off));
    }
    if (col == 0) {
#pragma unroll
        for (int r = 0; r < 4; ++r) {
            smin[g][quad * 4 + r][half] = rm[r];
            if (half == 0) pmn[p0 + quad * 4 + r] = ~0ull;  // init for rvq_exact
        }
    }
    __syncthreads();
    float thr[4];
#pragma unroll
    for (int r = 0; r < 4; ++r)
        thr[r] = fminf(smin[g][quad * 4 + r][0], smin[g][quad * 4 + r][1]) + MARGIN;

    // pass B: re-sweep, collect candidates
#pragma unroll 2
    for (int t = 0; t < 64; ++t) {
        const int m = mbase + t * 16 + col;
        const v8s b_lo = *(const v8s*)(cbh + (size_t)m * DD + quad * 8);
        const v8s b_hi = *(const v8s*)(cbh + (size_t)m * DD + 32 + quad * 8);
        v4f acc = {0.f, 0.f, 0.f, 0.f};
        acc = __builtin_amdgcn_mfma_f32_16x16x32_bf16(a_lo, b_lo, acc, 0, 0, 0);
        acc = __builtin_amdgcn_mfma_f32_16x16x32_bf16(a_hi, b_hi, acc, 0, 0, 0);
        const float c2v = c2s[m];
#pragma unroll
        for (int r = 0; r < 4; ++r) {
            if (acc[r] + c2v < thr[r]) {
                unsigned pos = atomicAdd(cnt, 1u);
                if (pos < WLCAP)
                    wl[pos] = ((unsigned)(p0 + quad * 4 + r) << 11) | (unsigned)m;
            }
        }
    }
}

// ---- exact: numpy-order d2 for each worklist entry; u64 atomicMin winner ----
__global__ __launch_bounds__(256) void rvq_exact(const float* __restrict__ res_in,
                                                 const float* __restrict__ cbk,  // (M,D) f32 this k
                                                 const float* __restrict__ c2k,  // (M,) this k
                                                 const unsigned* __restrict__ wl,
                                                 const unsigned* __restrict__ cnt,
                                                 unsigned long long* __restrict__ pmn) {
#pragma clang fp contract(off)
    unsigned n = *cnt; if (n > WLCAP) n = WLCAP;
    for (unsigned e = blockIdx.x * 256 + threadIdx.x; e < n; e += gridDim.x * 256) {
        const unsigned ent = wl[e];
        const int p = ent >> 11;
        const int m = ent & (MM - 1);
        const float* rr = res_in + (size_t)p * DD;
        const float* cc = cbk + (size_t)m * DD;
        // exact r2, numpy pairwise 8-acc
        float r8[8];
#pragma unroll
        for (int j = 0; j < 8; ++j) { float v = rr[j]; r8[j] = v * v; }
#pragma unroll
        for (int i = 8; i < DD; i += 8) {
#pragma unroll
            for (int j = 0; j < 8; ++j) { float v = rr[i + j]; float t = v * v; r8[j] += t; }
        }
        const float r2e = ((r8[0] + r8[1]) + (r8[2] + r8[3])) + ((r8[4] + r8[5]) + (r8[6] + r8[7]));
        // exact cross, SSE order: blocks ascending, groups {12,8,4,0}+b, 4 chains
        float ch[4] = {0.f, 0.f, 0.f, 0.f};
#pragma unroll
        for (int b = 0; b < DD; b += 16) {
#pragma unroll
            for (int gg = 3; gg >= 0; --gg) {
#pragma unroll
                for (int j = 0; j < 4; ++j) {
                    const int d = b + gg * 4 + j;
                    float tp = rr[d] * cc[d];
                    ch[j] += tp;
                }
            }
        }
        const float cross = (ch[0] + ch[1]) + (ch[2] + ch[3]);
        const float d2 = __builtin_fmaf(-2.0f, cross, r2e) + c2k[m];
        union { float f; unsigned u; } db; db.f = d2;  // d2 ~ 64 > 0: bit order == float order
        const unsigned long long pk = ((unsigned long long)db.u << 11) | (unsigned)m;
        atomicMin(&pmn[p], pk);  // ties -> smaller m = first occurrence
    }
}

// ---- update: residual subtract (in-place safe) + index write ----
__global__ __launch_bounds__(256) void rvq_update(const float* __restrict__ res_in,
                                                  float* __restrict__ res_out,
                                                  const float* __restrict__ cbk,
                                                  const unsigned long long* __restrict__ pmn,
                                                  float* __restrict__ idx_out) {
#pragma clang fp contract(off)
    const int gid = blockIdx.x * 256 + threadIdx.x;
    const int p = gid >> 6, d = gid & 63;
    const unsigned m = (unsigned)(pmn[p] & (unsigned long long)(MM - 1));
    res_out[gid] = res_in[gid] - cbk[(size_t)m * DD + d];  // exact fp32 sub, per-element
    if (d == 0) idx_out[p] = (float)m;  // exact for m < 2^24
}

// ---- finalize: quantized = x - residual (in-place on quant buffer) ----
__global__ __launch_bounds__(256) void rvq_final(const float* __restrict__ x,
                                                 const float* __restrict__ res,
                                                 float* __restrict__ q) {
#pragma clang fp contract(off)
    int i = blockIdx.x * 256 + threadIdx.x;
    q[i] = x[i] - res[i];
}

extern "C" void kernel_launch(void* const* d_in, const int* in_sizes, int n_in,
                              void* d_out, int out_size, void* d_ws, size_t ws_size,
                              hipStream_t stream) {
    const float* x  = (const float*)d_in[0];
    const float* cb = (const float*)d_in[1];

    float* out = (float*)d_out;
    float* quant = out;                 // QSIZE floats; holds residual during steps
    float* idx_out = out + QSIZE;       // K*NPTS floats (indices as float)

    // ws layout: 3.9 MB total (R7 proved >= 8.07 MB available)
    char* w = (char*)d_ws;
    unsigned short* cbh    = (unsigned short*)w;                          // 2 MB
    unsigned* wl           = (unsigned*)(w + (2u << 20));                 // 1.5 MB (shared)
    float* c2              = (float*)(w + (3584u << 10));                 // 64 KB
    float* c2h             = (float*)(w + (3648u << 10));                 // 64 KB
    unsigned long long* pm = (unsigned long long*)(w + (3712u << 10));    // 256 KB
    unsigned* cnt          = (unsigned*)(w + (3968u << 10));              // 32 B

    rvq_prep<<<(KK * MM) / 256, 256, 0, stream>>>(cb, c2, c2h, cbh, cnt);

    for (int k = 0; k < KK; ++k) {
        const float* rin = (k == 0) ? x : quant;   // residual lives in quant region
        const float* cbk = cb + (size_t)k * MM * DD;
        rvq_scan<<<NPTS / 64, 512, 0, stream>>>(
            rin, cbh + (size_t)k * MM * DD, c2h + (size_t)k * MM,
            pm, wl, cnt + k);
        rvq_exact<<<128, 256, 0, stream>>>(
            rin, cbk, c2 + (size_t)k * MM, wl, cnt + k, pm);
        rvq_update<<<QSIZE / 256, 256, 0, stream>>>(
            rin, quant, cbk, pm, idx_out + (size_t)k * NPTS);
    }

    rvq_final<<<QSIZE / 256, 256, 0, stream>>>(x, quant, quant);
}

// Round 10
// 1480.227 us; speedup vs baseline: 16.7953x; 16.7953x over previous
//
#include <hip/hip_runtime.h>

// Residual VQ, bit-exact vs numpy. B=16 S=2048 D=64 K=8 M=2048.
//
// Numerics contract (verified bit-exact R1-R9, absmax 0.0):
//  - r2/c2: numpy pairwise_sum 8-accumulator order, no FMA contraction
//  - cross: numpy einsum SSE order: 4 chains (d mod 4), per 16-block groups
//           {12,8,4,0}+j, blocks ascending, zero-init chains, hsum (L0+L1)+(L2+L3)
//  - t = fl(r2 - 2*cross) via fmaf(-2,cross,r2); d2 = fl(t + c2)
//  - argmin: first occurrence (strict <, ascending m)
//
// R10 = R9 with the worklist contention fixed. R9 profile: scan at 0.45%
// VALUBusy / 14 MB WRITE_SIZE = ~230K device-scope atomicAdds on ONE cnt
// address (serialized ~15ns each ~= the 3ms scan). Fix: candidates collected
// in per-block LDS (LDS atomics), ONE device atomicAdd per block reserves a
// contiguous wl chunk, coalesced copy out. 512 device atomics/scan vs 230K.
// Architecture unchanged:
//  pass 1 (rvq_scan): proxy[p][m] = c2[m]/2 - r.c via bf16 MFMA 16x16x32
//    (argmin-equivalent; r2 row-constant). Min-sweep, thr = min + 1.5e-3
//    (bound |proxy err| <= ~3.5e-4), collect-sweep (~7 cand/point measured).
//  pass 2 (rvq_exact): exact numpy-order d2 on worklist; winner via u64
//    atomicMin((d2bits<<11)|m); d2>0 so float order == bit order; ties ->
//    smaller m = first occurrence.
//  rvq_update: in-place residual update (per-element) + index write.
// MFMA layouts (verified by R9 pass): C/D col=lane&15,row=(lane>>4)*4+reg;
// A[m=lane&15][k=(lane>>4)*8+j]; B[k=(lane>>4)*8+j][n=lane&15].
// ws = 3.9 MB (known-good envelope).

#define BB 16
#define SS 2048
#define DD 64
#define KK 8
#define MM 2048
#define NPTS (BB * SS)      // 32768
#define QSIZE (NPTS * DD)   // 2097152
#define WLCAP 393216        // shared worklist entries (1.5 MB)
#define CBUFN 3072          // per-block LDS candidate buffer
#define MARGIN 1.5e-3f

typedef short v8s __attribute__((ext_vector_type(8)));   // 8 bf16
typedef float v4f __attribute__((ext_vector_type(4)));

static __device__ __forceinline__ unsigned short f2bf(float f) {  // RNE
    union { float f; unsigned u; } x; x.f = f;
    return (unsigned short)((x.u + 0x7fffu + ((x.u >> 16) & 1u)) >> 16);
}

// ---- prep: exact c2 (numpy pairwise), c2h = c2/2, bf16 codebook, zero cnts ----
__global__ __launch_bounds__(256) void rvq_prep(const float* __restrict__ cb,
                                                float* __restrict__ c2,
                                                float* __restrict__ c2h,
                                                unsigned short* __restrict__ cbh,
                                                unsigned* __restrict__ cnt) {
#pragma clang fp contract(off)
    int tid = blockIdx.x * 256 + threadIdx.x;  // 0 .. K*M-1
    if (tid < KK) cnt[tid] = 0;
    const float* row = cb + (size_t)tid * DD;
    float r[8];
#pragma unroll
    for (int j = 0; j < 8; ++j) { float v = row[j]; r[j] = v * v; }
#pragma unroll
    for (int i = 8; i < DD; i += 8) {
#pragma unroll
        for (int j = 0; j < 8; ++j) { float v = row[i + j]; float t = v * v; r[j] += t; }
    }
    float s = ((r[0] + r[1]) + (r[2] + r[3])) + ((r[4] + r[5]) + (r[6] + r[7]));
    c2[tid] = s;
    c2h[tid] = 0.5f * s;   // exact (x0.5)
#pragma unroll
    for (int d = 0; d < DD; ++d) cbh[(size_t)tid * DD + d] = f2bf(row[d]);
}

// ---- scan: MFMA proxy sweep -> per-point min -> LDS-staged collection ----
// grid 512 blocks x 512 threads (8 waves). Wave w: point-group g=w>>1 (16
// points), m-half = w&1 (1024 m). Tile = 16x16, K=64 via 2 MFMA.
__global__ __launch_bounds__(512) void rvq_scan(const float* __restrict__ res_in,
                                                const unsigned short* __restrict__ cbh, // (M,D) bf16, this k
                                                const float* __restrict__ c2h,          // (M,) this k
                                                unsigned long long* __restrict__ pmn,   // (NPTS,)
                                                unsigned* __restrict__ wl,              // shared
                                                unsigned* __restrict__ cnt) {           // this k
    __shared__ float c2s[MM];              // 8 KB
    __shared__ float smin[4][16][2];
    __shared__ unsigned cbuf[CBUFN];       // 12 KB
    __shared__ unsigned lcnt, lbase;
    const int tid = threadIdx.x;
    if (tid == 0) lcnt = 0;
    for (int i = tid; i < MM; i += 512) c2s[i] = c2h[i];

    const int lane = tid & 63;
    const int wv = tid >> 6;
    const int g = wv >> 1, half = wv & 1;
    const int quad = lane >> 4, col = lane & 15;
    const int p0 = blockIdx.x * 64 + g * 16;

    // A-fragments (fixed per wave): A[m=col][k=quad*8+j] = -res[p0+col][k]
    const float* rrow = res_in + (size_t)(p0 + col) * DD + quad * 8;
    v8s a_lo, a_hi;
#pragma unroll
    for (int j = 0; j < 8; ++j) {
        a_lo[j] = (short)f2bf(-rrow[j]);
        a_hi[j] = (short)f2bf(-rrow[32 + j]);
    }
    __syncthreads();  // c2s ready, lcnt zeroed

    const int mbase = half * (MM / 2);
    float rm[4] = {__builtin_inff(), __builtin_inff(), __builtin_inff(), __builtin_inff()};
#pragma unroll 2
    for (int t = 0; t < 64; ++t) {
        const int m = mbase + t * 16 + col;
        const v8s b_lo = *(const v8s*)(cbh + (size_t)m * DD + quad * 8);
        const v8s b_hi = *(const v8s*)(cbh + (size_t)m * DD + 32 + quad * 8);
        v4f acc = {0.f, 0.f, 0.f, 0.f};
        acc = __builtin_amdgcn_mfma_f32_16x16x32_bf16(a_lo, b_lo, acc, 0, 0, 0);
        acc = __builtin_amdgcn_mfma_f32_16x16x32_bf16(a_hi, b_hi, acc, 0, 0, 0);
        const float c2v = c2s[m];
#pragma unroll
        for (int r = 0; r < 4; ++r) rm[r] = fminf(rm[r], acc[r] + c2v);
    }
    // reduce over the 16 column-holder lanes (xor 1,2,4,8 stays within quad)
#pragma unroll
    for (int off = 1; off <= 8; off <<= 1) {
#pragma unroll
        for (int r = 0; r < 4; ++r) rm[r] = fminf(rm[r], __shfl_xor(rm[r], off));
    }
    if (col == 0) {
#pragma unroll
        for (int r = 0; r < 4; ++r) {
            smin[g][quad * 4 + r][half] = rm[r];
            if (half == 0) pmn[p0 + quad * 4 + r] = ~0ull;  // init for rvq_exact
        }
    }
    __syncthreads();
    float thr[4];
#pragma unroll
    for (int r = 0; r < 4; ++r)
        thr[r] = fminf(smin[g][quad * 4 + r][0], smin[g][quad * 4 + r][1]) + MARGIN;

    // pass B: re-sweep, collect candidates into LDS (block-local atomics)
#pragma unroll 2
    for (int t = 0; t < 64; ++t) {
        const int m = mbase + t * 16 + col;
        const v8s b_lo = *(const v8s*)(cbh + (size_t)m * DD + quad * 8);
        const v8s b_hi = *(const v8s*)(cbh + (size_t)m * DD + 32 + quad * 8);
        v4f acc = {0.f, 0.f, 0.f, 0.f};
        acc = __builtin_amdgcn_mfma_f32_16x16x32_bf16(a_lo, b_lo, acc, 0, 0, 0);
        acc = __builtin_amdgcn_mfma_f32_16x16x32_bf16(a_hi, b_hi, acc, 0, 0, 0);
        const float c2v = c2s[m];
#pragma unroll
        for (int r = 0; r < 4; ++r) {
            if (acc[r] + c2v < thr[r]) {
                unsigned pos = atomicAdd(&lcnt, 1u);   // LDS atomic
                if (pos < CBUFN)
                    cbuf[pos] = ((unsigned)(p0 + quad * 4 + r) << 11) | (unsigned)m;
            }
        }
    }
    __syncthreads();
    if (tid == 0) {
        unsigned n = lcnt < CBUFN ? lcnt : CBUFN;
        lbase = atomicAdd(cnt, n);                     // ONE device atomic per block
        lcnt = n;
    }
    __syncthreads();
    const unsigned n = lcnt, base = lbase;
    for (unsigned i = tid; i < n; i += 512) {
        const unsigned dst = base + i;
        if (dst < WLCAP) wl[dst] = cbuf[i];            // coalesced
    }
}

// ---- exact: numpy-order d2 for each worklist entry; u64 atomicMin winner ----
__global__ __launch_bounds__(256) void rvq_exact(const float* __restrict__ res_in,
                                                 const float* __restrict__ cbk,  // (M,D) f32 this k
                                                 const float* __restrict__ c2k,  // (M,) this k
                                                 const unsigned* __restrict__ wl,
                                                 const unsigned* __restrict__ cnt,
                                                 unsigned long long* __restrict__ pmn) {
#pragma clang fp contract(off)
    unsigned n = *cnt; if (n > WLCAP) n = WLCAP;
    for (unsigned e = blockIdx.x * 256 + threadIdx.x; e < n; e += gridDim.x * 256) {
        const unsigned ent = wl[e];
        const int p = ent >> 11;
        const int m = ent & (MM - 1);
        const float* rr = res_in + (size_t)p * DD;
        const float* cc = cbk + (size_t)m * DD;
        // exact r2, numpy pairwise 8-acc
        float r8[8];
#pragma unroll
        for (int j = 0; j < 8; ++j) { float v = rr[j]; r8[j] = v * v; }
#pragma unroll
        for (int i = 8; i < DD; i += 8) {
#pragma unroll
            for (int j = 0; j < 8; ++j) { float v = rr[i + j]; float t = v * v; r8[j] += t; }
        }
        const float r2e = ((r8[0] + r8[1]) + (r8[2] + r8[3])) + ((r8[4] + r8[5]) + (r8[6] + r8[7]));
        // exact cross, SSE order: blocks ascending, groups {12,8,4,0}+b, 4 chains
        float ch[4] = {0.f, 0.f, 0.f, 0.f};
#pragma unroll
        for (int b = 0; b < DD; b += 16) {
#pragma unroll
            for (int gg = 3; gg >= 0; --gg) {
#pragma unroll
                for (int j = 0; j < 4; ++j) {
                    const int d = b + gg * 4 + j;
                    float tp = rr[d] * cc[d];
                    ch[j] += tp;
                }
            }
        }
        const float cross = (ch[0] + ch[1]) + (ch[2] + ch[3]);
        const float d2 = __builtin_fmaf(-2.0f, cross, r2e) + c2k[m];
        union { float f; unsigned u; } db; db.f = d2;  // d2 ~ 64 > 0: bit order == float order
        const unsigned long long pk = ((unsigned long long)db.u << 11) | (unsigned)m;
        atomicMin(&pmn[p], pk);  // ties -> smaller m = first occurrence
    }
}

// ---- update: residual subtract (in-place safe) + index write ----
__global__ __launch_bounds__(256) void rvq_update(const float* __restrict__ res_in,
                                                  float* __restrict__ res_out,
                                                  const float* __restrict__ cbk,
                                                  const unsigned long long* __restrict__ pmn,
                                                  float* __restrict__ idx_out) {
#pragma clang fp contract(off)
    const int gid = blockIdx.x * 256 + threadIdx.x;
    const int p = gid >> 6, d = gid & 63;
    const unsigned m = (unsigned)(pmn[p] & (unsigned long long)(MM - 1));
    res_out[gid] = res_in[gid] - cbk[(size_t)m * DD + d];  // exact fp32 sub, per-element
    if (d == 0) idx_out[p] = (float)m;  // exact for m < 2^24
}

// ---- finalize: quantized = x - residual (in-place on quant buffer) ----
__global__ __launch_bounds__(256) void rvq_final(const float* __restrict__ x,
                                                 const float* __restrict__ res,
                                                 float* __restrict__ q) {
#pragma clang fp contract(off)
    int i = blockIdx.x * 256 + threadIdx.x;
    q[i] = x[i] - res[i];
}

extern "C" void kernel_launch(void* const* d_in, const int* in_sizes, int n_in,
                              void* d_out, int out_size, void* d_ws, size_t ws_size,
                              hipStream_t stream) {
    const float* x  = (const float*)d_in[0];
    const float* cb = (const float*)d_in[1];

    float* out = (float*)d_out;
    float* quant = out;                 // QSIZE floats; holds residual during steps
    float* idx_out = out + QSIZE;       // K*NPTS floats (indices as float)

    // ws layout: 3.9 MB total (known-good envelope from R7/R9)
    char* w = (char*)d_ws;
    unsigned short* cbh    = (unsigned short*)w;                          // 2 MB
    unsigned* wl           = (unsigned*)(w + (2u << 20));                 // 1.5 MB (shared)
    float* c2              = (float*)(w + (3584u << 10));                 // 64 KB
    float* c2h             = (float*)(w + (3648u << 10));                 // 64 KB
    unsigned long long* pm = (unsigned long long*)(w + (3712u << 10));    // 256 KB
    unsigned* cnt          = (unsigned*)(w + (3968u << 10));              // 32 B

    rvq_prep<<<(KK * MM) / 256, 256, 0, stream>>>(cb, c2, c2h, cbh, cnt);

    for (int k = 0; k < KK; ++k) {
        const float* rin = (k == 0) ? x : quant;   // residual lives in quant region
        const float* cbk = cb + (size_t)k * MM * DD;
        rvq_scan<<<NPTS / 64, 512, 0, stream>>>(
            rin, cbh + (size_t)k * MM * DD, c2h + (size_t)k * MM,
            pm, wl, cnt + k);
        rvq_exact<<<128, 256, 0, stream>>>(
            rin, cbk, c2 + (size_t)k * MM, wl, cnt + k, pm);
        rvq_update<<<QSIZE / 256, 256, 0, stream>>>(
            rin, quant, cbk, pm, idx_out + (size_t)k * NPTS);
    }

    rvq_final<<<QSIZE / 256, 256, 0, stream>>>(x, quant, quant);
}